// Round 9
// baseline (228.078 us; speedup 1.0000x reference)
//
#include <hip/hip_runtime.h>
#include <hip/hip_bf16.h>

typedef __attribute__((ext_vector_type(8))) short short8;
typedef __attribute__((ext_vector_type(4))) float f32x4;
typedef __attribute__((ext_vector_type(4))) float float4v;
typedef __attribute__((ext_vector_type(8))) unsigned short ushort8;
typedef __attribute__((ext_vector_type(4))) unsigned short ushort4v;

__device__ __forceinline__ unsigned short f2bf(float f) {
  union { float f; unsigned u; } a; a.f = f;
  unsigned u = a.u;
  u += 0x7FFFu + ((u >> 16) & 1u);   // RTNE
  return (unsigned short)(u >> 16);
}
__device__ __forceinline__ float bf2f(unsigned short h) {
  union { unsigned u; float f; } a; a.u = ((unsigned)h) << 16; return a.f;
}

__device__ __forceinline__ void gload_lds16(const void* g, void* l) {
  __builtin_amdgcn_global_load_lds(
      (const __attribute__((address_space(1))) unsigned int*)g,
      (__attribute__((address_space(3))) unsigned int*)l, 16, 0, 0);
}

// ---------------- f32 -> bf16 convert (vectorized, grid-stride) ----------------
__global__ void cvt_bf16(const float* __restrict__ in, unsigned short* __restrict__ out, long n) {
  long i = ((long)blockIdx.x * blockDim.x + threadIdx.x) * 4;
  long stride = (long)gridDim.x * blockDim.x * 4;
  for (; i < n; i += stride) {
    float4v x = *(const float4v*)(in + i);
    ushort4v o;
    o.x = f2bf(x.x); o.y = f2bf(x.y); o.z = f2bf(x.z); o.w = f2bf(x.w);
    *(ushort4v*)(out + i) = o;
  }
}

// ------------- transpose + convert: W[R][C] f32 -> WT[C][R] bf16 ---------------
__global__ void cvt_transpose(const float* __restrict__ in, unsigned short* __restrict__ out,
                              int R, int C) {
  __shared__ float tile[32][33];
  int c0 = blockIdx.x * 32, r0 = blockIdx.y * 32;
#pragma unroll
  for (int i = 0; i < 4; ++i) {
    int r = r0 + threadIdx.y + i * 8;
    tile[threadIdx.y + i * 8][threadIdx.x] = in[(long)r * C + c0 + threadIdx.x];
  }
  __syncthreads();
#pragma unroll
  for (int i = 0; i < 4; ++i) {
    int rr = threadIdx.y + i * 8;
    int cc = threadIdx.x;
    out[(long)(c0 + rr) * R + r0 + cc] = f2bf(tile[cc][rr]);
  }
}

__global__ void concat_bias(const float* __restrict__ a, const float* __restrict__ b,
                            float* __restrict__ o) {
  int i = blockIdx.x * 256 + threadIdx.x;   // 1024 total
  o[i] = (i < 512) ? a[i] : b[i - 512];
}

// ====== phased mod-3-buffered NT GEMM (256x128, BK=32, 2 blocks/CU) ======
// C[M,N] = A[M,K] * Bt[N,K]^T, bf16 in, f32 acc. 512 thr = 8 waves (4M x 2N),
// per-wave 64x64 out = acc[4][4] f32x4.
// LDS: 3 whole-K-tile buffers x 24KB (A 16KB + B 8KB) = 72KB -> TWO blocks/CU
// (16 waves/CU, forced by __launch_bounds__(512,4)); cross-block overlap fills
// barrier/LDS bubbles. Tile t -> buf t%3; iter t prefetches t+2 (3 gloads).
// Gate per iter: {vmcnt(3), s_barrier} - tile t landed, t+1's loads stay in
// flight ACROSS the barrier (counted vmcnt, never 0 mid-loop; cover = 2 iters).
// Each iter = 2 phases (m201 pattern): {ds_read subtile; issue gload;
// s_barrier; lgkmcnt(0)+sched_barrier; setprio(1); 8 MFMA; setprio(0);
// s_barrier} -> ds_reads fly during barrier-wait + other waves' MFMA.
// Race-free by mod-3: stage target untouched for >= 1 full iter after issue.
// Swizzle: LDS slot(r,s) = r*4 + (s^(r&3)) (16B slots, 4/row at BK=32);
// staging pre-swizzles the GLOBAL source so global_load_lds dest is linear;
// reads use the same XOR -> 2-way max bank aliasing (free, m136).
template<int OUT_BF16, int BIAS_MODE>  // BIAS: 0 none, 1 per-col, 2 per-row
__global__ __launch_bounds__(512, 4)
void gemmB(const unsigned short* __restrict__ A, int lda, long strideA,
           const unsigned short* __restrict__ Bt, int ldb, long strideB,
           void* __restrict__ Cv, int ldc, long strideC,
           const float* __restrict__ bias, float scale, int K,
           int MT, int NTt) {
  constexpr int AB = 16384;                // A: 256 rows * 64 B
  constexpr int BUFB = 24576;              // + B: 128 rows * 64 B
  __shared__ char lds[3 * BUFB];           // 73728 B

  const int tid = threadIdx.x;
  const int nb = gridDim.x, bid = blockIdx.x;         // nb % 8 == 0 always
  const int wg = (bid & 7) * (nb >> 3) + (bid >> 3);  // XCD-bijective swizzle
  const int ntile = wg % NTt;
  const int mtile = (wg / NTt) % MT;
  const int bz = wg / (NTt * MT);

  const unsigned short* Ab = A + bz * strideA + (long)(mtile * 256) * lda;
  const unsigned short* Bb = Bt + bz * strideB + (long)(ntile * 128) * ldb;

  const int wave = tid >> 6, lane = tid & 63;
  const int wm = wave >> 1, wn = wave & 1;
  const int lr = lane & 15, u = lane >> 4;

  // staging source offsets (elements): linear LDS slot q holds global
  // (row = q>>2, kslot = (q&3)^(row&3))
  long aoffg[2], boffg;
#pragma unroll
  for (int i = 0; i < 2; ++i) {
    int q = i * 512 + tid, r = q >> 2, s = (q & 3) ^ (r & 3);
    aoffg[i] = (long)r * lda + s * 8;
  }
  {
    int q = tid, r = q >> 2, s = (q & 3) ^ (r & 3);
    boffg = (long)r * ldb + s * 8;
  }
  const int t16 = tid * 16;

  // fragment read bases (bytes within one buffer); row&3 == lr&3 everywhere
  const int arow = (wm * 64 + lr) * 64;            // + mf*1024
  const int brow = AB + (wn * 64 + lr) * 64;       // + nf*1024
  const int sw = (u ^ (lr & 3)) << 4;              // k-slot u (u = 0..3)

  f32x4 acc[4][4];
#pragma unroll
  for (int m = 0; m < 4; ++m)
#pragma unroll
    for (int n = 0; n < 4; ++n) acc[m][n] = f32x4{0.f, 0.f, 0.f, 0.f};

  const int NT = K >> 5;

  // prologue: stage tile 0 -> buf0, tile 1 -> buf1 (6 loads in flight, FIFO)
#pragma unroll
  for (int tt = 0; tt < 2; ++tt) {
    char* lb = lds + tt * BUFB;
    const unsigned short* As = Ab + (tt << 5);
    const unsigned short* Bs = Bb + (tt << 5);
    gload_lds16(As + aoffg[0], lb + t16);
    gload_lds16(As + aoffg[1], lb + 8192 + t16);
    gload_lds16(Bs + boffg, lb + AB + t16);
  }

  int cb_ = 0, pb_ = 2;   // buf of tile t / tile t+2 (mod-3 counters)
  for (int t = 0; t < NT; ++t) {
    // gate: tile t landed; tile t+1's 3 loads stay in flight across the barrier
    if (t + 1 < NT) asm volatile("s_waitcnt vmcnt(3)" ::: "memory");
    else            asm volatile("s_waitcnt vmcnt(0)" ::: "memory");
    __builtin_amdgcn_s_barrier();

    const char* la = lds + cb_ * BUFB;
    char* lp = lds + pb_ * BUFB;
    const bool pf = (t + 2) < NT;
    const unsigned short* An = Ab + ((t + 2) << 5);
    const unsigned short* Bn = Bb + ((t + 2) << 5);

    // ---------- phase 0: read A(all) + B(nf 0,1); stage A of t+2 ----------
    short8 af[4], bf[2];
#pragma unroll
    for (int mf = 0; mf < 4; ++mf) af[mf] = *(const short8*)(la + arow + mf * 1024 + sw);
    bf[0] = *(const short8*)(la + brow + sw);
    bf[1] = *(const short8*)(la + brow + 1024 + sw);
    if (pf) {
      gload_lds16(An + aoffg[0], lp + t16);
      gload_lds16(An + aoffg[1], lp + 8192 + t16);
    }
    __builtin_amdgcn_s_barrier();              // reads fly during the wait
    asm volatile("s_waitcnt lgkmcnt(0)" ::: "memory");
    __builtin_amdgcn_sched_barrier(0);         // rule 18: fence after asm lgkm
    __builtin_amdgcn_s_setprio(1);
#pragma unroll
    for (int mf = 0; mf < 4; ++mf)
#pragma unroll
      for (int nf = 0; nf < 2; ++nf)
        acc[mf][nf] = __builtin_amdgcn_mfma_f32_16x16x32_bf16(af[mf], bf[nf], acc[mf][nf], 0, 0, 0);
    __builtin_amdgcn_s_setprio(0);
    __builtin_amdgcn_s_barrier();

    // ---------- phase 1: read B(nf 2,3); stage B of t+2 ----------
    short8 bg[2];
    bg[0] = *(const short8*)(la + brow + 2048 + sw);
    bg[1] = *(const short8*)(la + brow + 3072 + sw);
    if (pf) gload_lds16(Bn + boffg, lp + AB + t16);
    __builtin_amdgcn_s_barrier();
    asm volatile("s_waitcnt lgkmcnt(0)" ::: "memory");
    __builtin_amdgcn_sched_barrier(0);
    __builtin_amdgcn_s_setprio(1);
#pragma unroll
    for (int mf = 0; mf < 4; ++mf)
#pragma unroll
      for (int nf = 0; nf < 2; ++nf)
        acc[mf][nf + 2] = __builtin_amdgcn_mfma_f32_16x16x32_bf16(af[mf], bg[nf], acc[mf][nf + 2], 0, 0, 0);
    __builtin_amdgcn_s_setprio(0);
    // pin iter-t work before the next gate (back-edge ordering for staging safety)
    __builtin_amdgcn_sched_barrier(0);

    cb_ = (cb_ == 2) ? 0 : cb_ + 1;
    pb_ = (pb_ == 2) ? 0 : pb_ + 1;
  }

  // epilogue: C/D layout col = lane&15, row = (lane>>4)*4 + j
  const long cbase = (long)bz * strideC;
  const int row0 = mtile * 256 + wm * 64;
  const int col0 = ntile * 128 + wn * 64;
#pragma unroll
  for (int mf = 0; mf < 4; ++mf) {
#pragma unroll
    for (int nf = 0; nf < 4; ++nf) {
      const int col = col0 + nf * 16 + lr;
      float bc = (BIAS_MODE == 1) ? bias[col] : 0.f;
#pragma unroll
      for (int j = 0; j < 4; ++j) {
        const int row = row0 + mf * 16 + u * 4 + j;
        float val = acc[mf][nf][j] * scale + bc;
        if (BIAS_MODE == 2) val += bias[row];
        if (OUT_BF16)
          ((unsigned short*)Cv)[cbase + (long)row * ldc + col] = f2bf(val);
        else
          ((float*)Cv)[cbase + (long)row * ldc + col] = val;
      }
    }
  }
}

// ------- row softmax over bf16 scores, in place: [8192][2048] bf16 -------
__global__ __launch_bounds__(256)
void softmax_rows_bf16(unsigned short* __restrict__ sc) {
  long row = blockIdx.x;
  unsigned short* p = sc + row * 2048;
  int tid = threadIdx.x;
  int wave = tid >> 6;

  ushort8 x = *(const ushort8*)(p + tid * 8);
  float v[8];
#pragma unroll
  for (int j = 0; j < 8; ++j) v[j] = bf2f(x[j]);

  float m = -1e30f;
#pragma unroll
  for (int j = 0; j < 8; ++j) m = fmaxf(m, v[j]);
#pragma unroll
  for (int o = 32; o; o >>= 1) m = fmaxf(m, __shfl_xor(m, o));
  __shared__ float redm[4], reds[4];
  if ((tid & 63) == 0) redm[wave] = m;
  __syncthreads();
  m = fmaxf(fmaxf(redm[0], redm[1]), fmaxf(redm[2], redm[3]));

  float s = 0.f;
#pragma unroll
  for (int j = 0; j < 8; ++j) { v[j] = __expf(v[j] - m); s += v[j]; }
#pragma unroll
  for (int o = 32; o; o >>= 1) s += __shfl_xor(s, o);
  if ((tid & 63) == 0) reds[wave] = s;
  __syncthreads();
  s = reds[0] + reds[1] + reds[2] + reds[3];
  float inv = 1.0f / s;

  ushort8 o8;
#pragma unroll
  for (int j = 0; j < 8; ++j) o8[j] = f2bf(v[j] * inv);
  *(ushort8*)(p + tid * 8) = o8;
}

// ------------------------------------------------------------------------------
extern "C" void kernel_launch(void* const* d_in, const int* in_sizes, int n_in,
                              void* d_out, int out_size, void* d_ws, size_t ws_size,
                              hipStream_t stream) {
  const float* X  = (const float*)d_in[0];
  const float* Wq = (const float*)d_in[1];
  const float* bq = (const float*)d_in[2];
  const float* Wk = (const float*)d_in[3];
  const float* bk = (const float*)d_in[4];
  const float* Wv = (const float*)d_in[5];
  const float* bv = (const float*)d_in[6];
  float* out = (float*)d_out;

  char* ws = (char*)d_ws;
  unsigned short* Xb   = (unsigned short*)(ws);                 // 16 MiB [8192,1024]
  unsigned short* WqkT = (unsigned short*)(ws + (16l << 20));   //  2 MiB [1024,1024] (rows 0-511 Wq^T, 512-1023 Wk^T)
  unsigned short* WvT  = (unsigned short*)(ws + (18l << 20));   //  2 MiB [1024,1024]
  float*          bqk  = (float*)         (ws + (20l << 20));   //  4 KiB [1024]
  unsigned short* QKb  = (unsigned short*)(ws + (21l << 20));   // 16 MiB [8192,1024] (cols 0-511 Q, 512-1023 K)
  unsigned short* VT   = (unsigned short*)(ws + (37l << 20));   // 16 MiB [1024,8192]
  unsigned short* SC   = (unsigned short*)(ws + (53l << 20));   // 32 MiB [4][2048][2048] bf16

  // 1) conversions / layout prep
  cvt_bf16<<<4096, 256, 0, stream>>>(X, Xb, 8388608);
  cvt_transpose<<<dim3(16, 32), dim3(32, 8), 0, stream>>>(Wq, WqkT, 1024, 512);
  cvt_transpose<<<dim3(16, 32), dim3(32, 8), 0, stream>>>(Wk, WqkT + 512 * 1024, 1024, 512);
  cvt_transpose<<<dim3(32, 32), dim3(32, 8), 0, stream>>>(Wv, WvT, 1024, 1024);
  concat_bias<<<4, 256, 0, stream>>>(bq, bk, bqk);

  // 2) fused Q|K projection: QKb = Xb * WqkT^T + [bq;bk]  (bf16 out)
  gemmB<1, 1><<<256, 512, 0, stream>>>(Xb, 1024, 0, WqkT, 1024, 0,
                                       QKb, 1024, 0, bqk, 1.f, 1024, 32, 8);
  // V^T[1024,8192] = WvT * Xb^T (+ bv per-row), bf16 out
  gemmB<1, 2><<<256, 512, 0, stream>>>(WvT, 1024, 0, Xb, 1024, 0,
                                       VT, 8192, 0, bv, 1.f, 1024, 4, 64);

  // 3) scores[b] = Q[b] K[b]^T / sqrt(512)  (bf16 out, batched)
  gemmB<1, 0><<<512, 512, 0, stream>>>(QKb, 1024, 2048l * 1024, QKb + 512, 1024, 2048l * 1024,
                                       SC, 2048, 2048l * 2048, nullptr,
                                       0.044194173824159216f, 512, 8, 16);

  // 4) softmax rows, bf16 in-place
  softmax_rows_bf16<<<8192, 256, 0, stream>>>(SC);

  // 5) out[b] = P[b] V[b]  (A = P bf16 lda 2048; Bt = V^T batch slice)
  gemmB<0, 0><<<256, 512, 0, stream>>>(SC, 2048, 2048l * 2048, VT, 8192, 2048,
                                       out, 1024, 2048l * 1024, nullptr, 1.f, 2048, 8, 8);
}

// Round 10
// 223.846 us; speedup vs baseline: 1.0189x; 1.0189x over previous
//
#include <hip/hip_runtime.h>
#include <hip/hip_bf16.h>

typedef __attribute__((ext_vector_type(8))) short short8;
typedef __attribute__((ext_vector_type(4))) float f32x4;
typedef __attribute__((ext_vector_type(4))) float float4v;
typedef __attribute__((ext_vector_type(8))) unsigned short ushort8;
typedef __attribute__((ext_vector_type(4))) unsigned short ushort4v;

__device__ __forceinline__ unsigned short f2bf(float f) {
  union { float f; unsigned u; } a; a.f = f;
  unsigned u = a.u;
  u += 0x7FFFu + ((u >> 16) & 1u);   // RTNE
  return (unsigned short)(u >> 16);
}
__device__ __forceinline__ float bf2f(unsigned short h) {
  union { unsigned u; float f; } a; a.u = ((unsigned)h) << 16; return a.f;
}

__device__ __forceinline__ void gload_lds16(const void* g, void* l) {
  __builtin_amdgcn_global_load_lds(
      (const __attribute__((address_space(1))) unsigned int*)g,
      (__attribute__((address_space(3))) unsigned int*)l, 16, 0, 0);
}

// ---------------- f32 -> bf16 convert (vectorized, grid-stride) ----------------
__global__ void cvt_bf16(const float* __restrict__ in, unsigned short* __restrict__ out, long n) {
  long i = ((long)blockIdx.x * blockDim.x + threadIdx.x) * 4;
  long stride = (long)gridDim.x * blockDim.x * 4;
  for (; i < n; i += stride) {
    float4v x = *(const float4v*)(in + i);
    ushort4v o;
    o.x = f2bf(x.x); o.y = f2bf(x.y); o.z = f2bf(x.z); o.w = f2bf(x.w);
    *(ushort4v*)(out + i) = o;
  }
}

// ------------- transpose + convert: W[R][C] f32 -> WT[C][R] bf16 ---------------
__global__ void cvt_transpose(const float* __restrict__ in, unsigned short* __restrict__ out,
                              int R, int C) {
  __shared__ float tile[32][33];
  int c0 = blockIdx.x * 32, r0 = blockIdx.y * 32;
#pragma unroll
  for (int i = 0; i < 4; ++i) {
    int r = r0 + threadIdx.y + i * 8;
    tile[threadIdx.y + i * 8][threadIdx.x] = in[(long)r * C + c0 + threadIdx.x];
  }
  __syncthreads();
#pragma unroll
  for (int i = 0; i < 4; ++i) {
    int rr = threadIdx.y + i * 8;
    int cc = threadIdx.x;
    out[(long)(c0 + rr) * R + r0 + cc] = f2bf(tile[cc][rr]);
  }
}

__global__ void concat_bias(const float* __restrict__ a, const float* __restrict__ b,
                            float* __restrict__ o) {
  int i = blockIdx.x * 256 + threadIdx.x;   // 1024 total
  o[i] = (i < 512) ? a[i] : b[i - 512];
}

// ========== m97-replica NT GEMM: 128x128 tile, BK=32, 4 blocks/CU ==========
// C[M,N] = A[M,K] * Bt[N,K]^T, bf16 in, f32 acc. 256 thr = 4 waves (2M x 2N),
// per-wave 64x64 out = acc[4][4] f32x4.
// LDS: double-buffer 2 x (A 8KB + B 8KB) = 32KB -> with __launch_bounds__(256,4)
// => 4 blocks/CU = 16 waves/CU. The verified m97 mechanism (912 TF): one plain
// __syncthreads() per K-iter (compiler drains vmcnt+lgkm at the barrier);
// cross-BLOCK wave overlap hides the drain stall - no fragile asm pipeline.
// Race audit: iter t reads buf t&1 (reads complete at the barrier via lgkmcnt),
// stages tile t+1 into buf (t+1)&1 (drained at the same barrier); buf t&1 is
// only overwritten by iter t+1's stage of tile t+2, after the barrier. Safe.
// Swizzle (BK=32, 64B rows): LDS 16B-slot(r,s) holds source k-slot s^((r>>1)&3).
// Read side: lane(lr,u) reads slot u^((lr>>1)&3) -> recovers source slot u;
// bank_start = 16*(lr&1)+4*((lr>>1)&3 ^ u) covers 8 distinct starts per
// 16-lane quarter -> 2-way max (free, m136). Staging writes are linear (tid*16).
template<int OUT_BF16, int BIAS_MODE>  // BIAS: 0 none, 1 per-col, 2 per-row
__global__ __launch_bounds__(256, 4)
void gemmC(const unsigned short* __restrict__ A, int lda, long strideA,
           const unsigned short* __restrict__ Bt, int ldb, long strideB,
           void* __restrict__ Cv, int ldc, long strideC,
           const float* __restrict__ bias, float scale, int K,
           int MT, int NTt) {
  constexpr int AB = 8192;                 // A: 128 rows * 64 B
  constexpr int BUFB = 16384;              // + B: 128 rows * 64 B
  __shared__ char lds[2 * BUFB];           // 32768 B

  const int tid = threadIdx.x;
  const int nb = gridDim.x, bid = blockIdx.x;         // nb % 8 == 0 always
  const int wg = (bid & 7) * (nb >> 3) + (bid >> 3);  // XCD-bijective swizzle
  const int ntile = wg % NTt;
  const int mtile = (wg / NTt) % MT;
  const int bz = wg / (NTt * MT);

  const unsigned short* Ab = A + bz * strideA + (long)(mtile * 128) * lda;
  const unsigned short* Bb = Bt + bz * strideB + (long)(ntile * 128) * ldb;

  const int wave = tid >> 6, lane = tid & 63;
  const int wm = wave >> 1, wn = wave & 1;
  const int lr = lane & 15, u = lane >> 4;

  // staging source offsets (elements): linear LDS slot q (16B) holds global
  // (row = q>>2, k-slot = (q&3) ^ ((row>>1)&3))  [bijective per row]
  long aoffg[2], boffg[2];
#pragma unroll
  for (int i = 0; i < 2; ++i) {
    int q = i * 256 + tid, r = q >> 2, s = (q & 3) ^ ((r >> 1) & 3);
    aoffg[i] = (long)r * lda + s * 8;
    boffg[i] = (long)r * ldb + s * 8;
  }
  const int t16 = tid * 16;

  // fragment read bases; frag row R = (w*64 + f*16 + lr) => (R>>1)&3 == (lr>>1)&3
  const int arow = (wm * 64 + lr) * 64;          // + mf*1024
  const int brow = AB + (wn * 64 + lr) * 64;     // + nf*1024
  const int sw = (u ^ ((lr >> 1) & 3)) << 4;     // recovers source k-slot u

  f32x4 acc[4][4];
#pragma unroll
  for (int m = 0; m < 4; ++m)
#pragma unroll
    for (int n = 0; n < 4; ++n) acc[m][n] = f32x4{0.f, 0.f, 0.f, 0.f};

  const int NT = K >> 5;

  // prologue: stage tile 0 -> buf0
  {
    char* lb = lds;
    gload_lds16(Ab + aoffg[0], lb + t16);
    gload_lds16(Ab + aoffg[1], lb + 4096 + t16);
    gload_lds16(Bb + boffg[0], lb + AB + t16);
    gload_lds16(Bb + boffg[1], lb + AB + 4096 + t16);
  }
  __syncthreads();

  for (int t = 0; t < NT; ++t) {
    // stage tile t+1 -> other buffer (drained by this iter's __syncthreads)
    if (t + 1 < NT) {
      char* lp = lds + ((t + 1) & 1) * BUFB;
      const unsigned short* An = Ab + ((t + 1) << 5);
      const unsigned short* Bn = Bb + ((t + 1) << 5);
      gload_lds16(An + aoffg[0], lp + t16);
      gload_lds16(An + aoffg[1], lp + 4096 + t16);
      gload_lds16(Bn + boffg[0], lp + AB + t16);
      gload_lds16(Bn + boffg[1], lp + AB + 4096 + t16);
    }

    const char* la = lds + (t & 1) * BUFB;
    short8 af[4], bf[4];
#pragma unroll
    for (int mf = 0; mf < 4; ++mf) af[mf] = *(const short8*)(la + arow + mf * 1024 + sw);
#pragma unroll
    for (int nf = 0; nf < 4; ++nf) bf[nf] = *(const short8*)(la + brow + nf * 1024 + sw);

    __builtin_amdgcn_s_setprio(1);
#pragma unroll
    for (int mf = 0; mf < 4; ++mf)
#pragma unroll
      for (int nf = 0; nf < 4; ++nf)
        acc[mf][nf] = __builtin_amdgcn_mfma_f32_16x16x32_bf16(af[mf], bf[nf], acc[mf][nf], 0, 0, 0);
    __builtin_amdgcn_s_setprio(0);

    __syncthreads();   // drains stage loads (vmcnt0) + read completion (lgkm0)
  }

  // epilogue: C/D layout col = lane&15, row = (lane>>4)*4 + j
  const long cbase = (long)bz * strideC;
  const int row0 = mtile * 128 + wm * 64;
  const int col0 = ntile * 128 + wn * 64;
#pragma unroll
  for (int mf = 0; mf < 4; ++mf) {
#pragma unroll
    for (int nf = 0; nf < 4; ++nf) {
      const int col = col0 + nf * 16 + lr;
      float bc = (BIAS_MODE == 1) ? bias[col] : 0.f;
#pragma unroll
      for (int j = 0; j < 4; ++j) {
        const int row = row0 + mf * 16 + u * 4 + j;
        float val = acc[mf][nf][j] * scale + bc;
        if (BIAS_MODE == 2) val += bias[row];
        if (OUT_BF16)
          ((unsigned short*)Cv)[cbase + (long)row * ldc + col] = f2bf(val);
        else
          ((float*)Cv)[cbase + (long)row * ldc + col] = val;
      }
    }
  }
}

// ------- row softmax over bf16 scores, in place: [8192][2048] bf16 -------
__global__ __launch_bounds__(256)
void softmax_rows_bf16(unsigned short* __restrict__ sc) {
  long row = blockIdx.x;
  unsigned short* p = sc + row * 2048;
  int tid = threadIdx.x;
  int wave = tid >> 6;

  ushort8 x = *(const ushort8*)(p + tid * 8);
  float v[8];
#pragma unroll
  for (int j = 0; j < 8; ++j) v[j] = bf2f(x[j]);

  float m = -1e30f;
#pragma unroll
  for (int j = 0; j < 8; ++j) m = fmaxf(m, v[j]);
#pragma unroll
  for (int o = 32; o; o >>= 1) m = fmaxf(m, __shfl_xor(m, o));
  __shared__ float redm[4], reds[4];
  if ((tid & 63) == 0) redm[wave] = m;
  __syncthreads();
  m = fmaxf(fmaxf(redm[0], redm[1]), fmaxf(redm[2], redm[3]));

  float s = 0.f;
#pragma unroll
  for (int j = 0; j < 8; ++j) { v[j] = __expf(v[j] - m); s += v[j]; }
#pragma unroll
  for (int o = 32; o; o >>= 1) s += __shfl_xor(s, o);
  if ((tid & 63) == 0) reds[wave] = s;
  __syncthreads();
  s = reds[0] + reds[1] + reds[2] + reds[3];
  float inv = 1.0f / s;

  ushort8 o8;
#pragma unroll
  for (int j = 0; j < 8; ++j) o8[j] = f2bf(v[j] * inv);
  *(ushort8*)(p + tid * 8) = o8;
}

// ------------------------------------------------------------------------------
extern "C" void kernel_launch(void* const* d_in, const int* in_sizes, int n_in,
                              void* d_out, int out_size, void* d_ws, size_t ws_size,
                              hipStream_t stream) {
  const float* X  = (const float*)d_in[0];
  const float* Wq = (const float*)d_in[1];
  const float* bq = (const float*)d_in[2];
  const float* Wk = (const float*)d_in[3];
  const float* bk = (const float*)d_in[4];
  const float* Wv = (const float*)d_in[5];
  const float* bv = (const float*)d_in[6];
  float* out = (float*)d_out;

  char* ws = (char*)d_ws;
  unsigned short* Xb   = (unsigned short*)(ws);                 // 16 MiB [8192,1024]
  unsigned short* WqkT = (unsigned short*)(ws + (16l << 20));   //  2 MiB [1024,1024] (rows 0-511 Wq^T, 512-1023 Wk^T)
  unsigned short* WvT  = (unsigned short*)(ws + (18l << 20));   //  2 MiB [1024,1024]
  float*          bqk  = (float*)         (ws + (20l << 20));   //  4 KiB [1024]
  unsigned short* QKb  = (unsigned short*)(ws + (21l << 20));   // 16 MiB [8192,1024] (cols 0-511 Q, 512-1023 K)
  unsigned short* VT   = (unsigned short*)(ws + (37l << 20));   // 16 MiB [1024,8192]
  unsigned short* SC   = (unsigned short*)(ws + (53l << 20));   // 32 MiB [4][2048][2048] bf16

  // 1) conversions / layout prep
  cvt_bf16<<<4096, 256, 0, stream>>>(X, Xb, 8388608);
  cvt_transpose<<<dim3(16, 32), dim3(32, 8), 0, stream>>>(Wq, WqkT, 1024, 512);
  cvt_transpose<<<dim3(16, 32), dim3(32, 8), 0, stream>>>(Wk, WqkT + 512 * 1024, 1024, 512);
  cvt_transpose<<<dim3(32, 32), dim3(32, 8), 0, stream>>>(Wv, WvT, 1024, 1024);
  concat_bias<<<4, 256, 0, stream>>>(bq, bk, bqk);

  // 2) fused Q|K projection: QKb = Xb * WqkT^T + [bq;bk]  (bf16 out; grid 512)
  gemmC<1, 1><<<512, 256, 0, stream>>>(Xb, 1024, 0, WqkT, 1024, 0,
                                       QKb, 1024, 0, bqk, 1.f, 1024, 64, 8);
  // V^T[1024,8192] = WvT * Xb^T (+ bv per-row), bf16 out (grid 512)
  gemmC<1, 2><<<512, 256, 0, stream>>>(WvT, 1024, 0, Xb, 1024, 0,
                                       VT, 8192, 0, bv, 1.f, 1024, 8, 64);

  // 3) scores[b] = Q[b] K[b]^T / sqrt(512)  (bf16 out, batched; grid 1024)
  gemmC<1, 0><<<1024, 256, 0, stream>>>(QKb, 1024, 2048l * 1024, QKb + 512, 1024, 2048l * 1024,
                                        SC, 2048, 2048l * 2048, nullptr,
                                        0.044194173824159216f, 512, 16, 16);

  // 4) softmax rows, bf16 in-place
  softmax_rows_bf16<<<8192, 256, 0, stream>>>(SC);

  // 5) out[b] = P[b] V[b]  (A = P bf16 lda 2048; Bt = V^T batch slice; grid 512)
  gemmC<0, 0><<<512, 256, 0, stream>>>(SC, 2048, 2048l * 2048, VT, 8192, 2048,
                                       out, 1024, 2048l * 1024, nullptr, 1.f, 2048, 16, 8);
}

// Round 13
// 221.826 us; speedup vs baseline: 1.0282x; 1.0091x over previous
//
#include <hip/hip_runtime.h>
#include <hip/hip_bf16.h>

typedef __attribute__((ext_vector_type(8))) short short8;
typedef __attribute__((ext_vector_type(4))) float f32x4;
typedef __attribute__((ext_vector_type(4))) float float4v;
typedef __attribute__((ext_vector_type(8))) unsigned short ushort8;
typedef __attribute__((ext_vector_type(4))) unsigned short ushort4v;

__device__ __forceinline__ unsigned short f2bf(float f) {
  union { float f; unsigned u; } a; a.f = f;
  unsigned u = a.u;
  u += 0x7FFFu + ((u >> 16) & 1u);   // RTNE
  return (unsigned short)(u >> 16);
}
__device__ __forceinline__ float bf2f(unsigned short h) {
  union { unsigned u; float f; } a; a.u = ((unsigned)h) << 16; return a.f;
}

__device__ __forceinline__ void gload_lds16(const void* g, void* l) {
  __builtin_amdgcn_global_load_lds(
      (const __attribute__((address_space(1))) unsigned int*)g,
      (__attribute__((address_space(3))) unsigned int*)l, 16, 0, 0);
}

// ================= merged prep: X->bf16, W transposes, bias concat =================
// blocks [0,2048): convert X (8388608 f32 -> bf16), 4 vec4-iters/thread
// blocks [2048,2560): Wq^T -> WqkT rows 0-511     (in 1024x512)
// blocks [2560,3072): Wk^T -> WqkT rows 512-1023
// blocks [3072,4096): Wv^T -> WvT                  (in 1024x1024)
// blocks [4096,4100): bqk = [bq;bk]
__global__ __launch_bounds__(256)
void prep(const float* __restrict__ X, unsigned short* __restrict__ Xb,
          const float* __restrict__ Wq, const float* __restrict__ Wk,
          const float* __restrict__ Wv,
          unsigned short* __restrict__ WqkT, unsigned short* __restrict__ WvT,
          const float* __restrict__ bq, const float* __restrict__ bk,
          float* __restrict__ bqk) {
  __shared__ float tile[32][33];
  const int b = blockIdx.x, tid = threadIdx.x;
  if (b < 2048) {
    long i = ((long)b * 256 + tid) * 4;
    const long stride = 2048l * 256 * 4;
#pragma unroll
    for (int it = 0; it < 4; ++it, i += stride) {
      float4v x = *(const float4v*)(X + i);
      ushort4v o;
      o.x = f2bf(x.x); o.y = f2bf(x.y); o.z = f2bf(x.z); o.w = f2bf(x.w);
      *(ushort4v*)(Xb + i) = o;
    }
  } else if (b < 4096) {
    const float* in; unsigned short* outp; int C, tb;
    if (b < 2560)      { in = Wq; outp = WqkT;              C = 512;  tb = b - 2048; }
    else if (b < 3072) { in = Wk; outp = WqkT + 512 * 1024; C = 512;  tb = b - 2560; }
    else               { in = Wv; outp = WvT;               C = 1024; tb = b - 3072; }
    const int nbx = C >> 5;
    const int c0 = (tb % nbx) * 32, r0 = (tb / nbx) * 32;   // R = 1024 rows always
    const int tx = tid & 31, ty = tid >> 5;                  // 32 x 8
#pragma unroll
    for (int i = 0; i < 4; ++i) {
      int r = r0 + ty + i * 8;
      tile[ty + i * 8][tx] = in[(long)r * C + c0 + tx];
    }
    __syncthreads();
#pragma unroll
    for (int i = 0; i < 4; ++i) {
      int rr = ty + i * 8;   // out row within tile (= in col)
      int cc = tx;           // out col within tile (= in row)
      outp[(long)(c0 + rr) * 1024 + r0 + cc] = f2bf(tile[cc][rr]);
    }
  } else {
    int i = (b - 4096) * 256 + tid;   // [0,1024)
    bqk[i] = (i < 512) ? bq[i] : bk[i - 512];
  }
}

// ========== shared GEMM core (m97-replica): 128x128 tile, BK=32 ==========
// C[M,N] = A[M,K] * Bt[N,K]^T, bf16 in, f32 acc. 256 thr = 4 waves (2M x 2N),
// per-wave 64x64 out = acc[4][4] f32x4. LDS dbuf 2x16KB = 32KB; one plain
// __syncthreads() per K-iter (compiler drains vmcnt+lgkm); cross-block wave
// overlap (up to 4 blocks/CU) hides the drain. Swizzle (BK=32, 64B rows):
// LDS 16B-slot(r,s) holds source k-slot s^((r>>1)&3); read slot u^((lr>>1)&3)
// -> 8 distinct bank-starts per 16-lane quarter (2-way max, free; verified
// 0 conflicts in round 10). Staging writes linear (tid*16); source pre-swizzled.
// EPILOGUE FIX vs round 11: wave offsets wm*64 / wn*64 restored (round-11
// refactor dropped them -> all 4 waves wrote the same quadrant -> zeros).
template<int OUT_BF16>
__device__ __forceinline__ void gemm_core(
    char* lds,
    const unsigned short* __restrict__ Ab, int lda,
    const unsigned short* __restrict__ Bb, int ldb,
    void* __restrict__ Cv, int ldc, long cbase,
    const float* __restrict__ bias, int bias_mode, float scale, int K,
    int row0base, int col0base) {
  constexpr int AB = 8192, BUFB = 16384;
  const int tid = threadIdx.x;
  const int wave = tid >> 6, lane = tid & 63;
  const int wm = wave >> 1, wn = wave & 1;
  const int lr = lane & 15, u = lane >> 4;

  long aoffg[2], boffg[2];
#pragma unroll
  for (int i = 0; i < 2; ++i) {
    int q = i * 256 + tid, r = q >> 2, s = (q & 3) ^ ((r >> 1) & 3);
    aoffg[i] = (long)r * lda + s * 8;
    boffg[i] = (long)r * ldb + s * 8;
  }
  const int t16 = tid * 16;

  const int arow = (wm * 64 + lr) * 64;          // + mf*1024
  const int brow = AB + (wn * 64 + lr) * 64;     // + nf*1024
  const int sw = (u ^ ((lr >> 1) & 3)) << 4;     // recovers source k-slot u

  f32x4 acc[4][4];
#pragma unroll
  for (int m = 0; m < 4; ++m)
#pragma unroll
    for (int n = 0; n < 4; ++n) acc[m][n] = f32x4{0.f, 0.f, 0.f, 0.f};

  const int NT = K >> 5;

  {  // prologue: stage tile 0 -> buf0
    char* lb = lds;
    gload_lds16(Ab + aoffg[0], lb + t16);
    gload_lds16(Ab + aoffg[1], lb + 4096 + t16);
    gload_lds16(Bb + boffg[0], lb + AB + t16);
    gload_lds16(Bb + boffg[1], lb + AB + 4096 + t16);
  }
  __syncthreads();

  for (int t = 0; t < NT; ++t) {
    if (t + 1 < NT) {   // stage tile t+1 -> other buffer
      char* lp = lds + ((t + 1) & 1) * BUFB;
      const unsigned short* An = Ab + ((t + 1) << 5);
      const unsigned short* Bn = Bb + ((t + 1) << 5);
      gload_lds16(An + aoffg[0], lp + t16);
      gload_lds16(An + aoffg[1], lp + 4096 + t16);
      gload_lds16(Bn + boffg[0], lp + AB + t16);
      gload_lds16(Bn + boffg[1], lp + AB + 4096 + t16);
    }

    const char* la = lds + (t & 1) * BUFB;
    short8 af[4], bf[4];
#pragma unroll
    for (int mf = 0; mf < 4; ++mf) af[mf] = *(const short8*)(la + arow + mf * 1024 + sw);
#pragma unroll
    for (int nf = 0; nf < 4; ++nf) bf[nf] = *(const short8*)(la + brow + nf * 1024 + sw);

    __builtin_amdgcn_s_setprio(1);
#pragma unroll
    for (int mf = 0; mf < 4; ++mf)
#pragma unroll
      for (int nf = 0; nf < 4; ++nf)
        acc[mf][nf] = __builtin_amdgcn_mfma_f32_16x16x32_bf16(af[mf], bf[nf], acc[mf][nf], 0, 0, 0);
    __builtin_amdgcn_s_setprio(0);

    __syncthreads();   // drains stage loads (vmcnt0) + read completion (lgkm0)
  }

  // epilogue: C/D layout col = lane&15, row = (lane>>4)*4 + j
  const int row0 = row0base + wm * 64;   // FIX: wave-row offset restored
  const int col0 = col0base + wn * 64;   // FIX: wave-col offset restored
#pragma unroll
  for (int mf = 0; mf < 4; ++mf) {
#pragma unroll
    for (int nf = 0; nf < 4; ++nf) {
      const int col = col0 + nf * 16 + lr;
      float bc = (bias_mode == 1) ? bias[col] : 0.f;
#pragma unroll
      for (int j = 0; j < 4; ++j) {
        const int row = row0 + mf * 16 + u * 4 + j;
        float val = acc[mf][nf][j] * scale + bc;
        if (bias_mode == 2) val += bias[row];
        if (OUT_BF16)
          ((unsigned short*)Cv)[cbase + (long)row * ldc + col] = f2bf(val);
        else
          ((float*)Cv)[cbase + (long)row * ldc + col] = val;
      }
    }
  }
}

// ---------------- plain batched NT GEMM wrapper (no bias) ----------------
template<int OUT_BF16>
__global__ __launch_bounds__(256, 4)
void gemmC(const unsigned short* __restrict__ A, int lda, long strideA,
           const unsigned short* __restrict__ Bt, int ldb, long strideB,
           void* __restrict__ Cv, int ldc, long strideC,
           float scale, int K, int MT, int NTt) {
  __shared__ char lds[32768];
  const int nb = gridDim.x, bid = blockIdx.x;         // nb % 8 == 0 always
  const int wg = (bid & 7) * (nb >> 3) + (bid >> 3);  // XCD-bijective swizzle
  const int ntile = wg % NTt;
  const int mtile = (wg / NTt) % MT;
  const int bz = wg / (NTt * MT);
  gemm_core<OUT_BF16>(lds,
      A + bz * strideA + (long)(mtile * 128) * lda, lda,
      Bt + bz * strideB + (long)(ntile * 128) * ldb, ldb,
      Cv, ldc, (long)bz * strideC, nullptr, 0, scale, K,
      mtile * 128, ntile * 128);
}

// ------- merged projections: blocks [0,512) QK-proj, [512,1024) V-proj -------
// QK: QKb[8192,1024] = Xb * WqkT^T + [bq;bk] (per-col bias), MT=64, NTt=8
// V : VT[1024,8192]  = WvT * Xb^T  + bv      (per-row bias), MT=8,  NTt=64
__global__ __launch_bounds__(256, 4)
void gemmProj(const unsigned short* __restrict__ Xb,
              const unsigned short* __restrict__ WqkT,
              const unsigned short* __restrict__ WvT,
              unsigned short* __restrict__ QKb, unsigned short* __restrict__ VT,
              const float* __restrict__ bqk, const float* __restrict__ bv) {
  __shared__ char lds[32768];
  const bool isqk = blockIdx.x < 512;
  const int bid = isqk ? blockIdx.x : (blockIdx.x - 512);
  const int wg = (bid & 7) * 64 + (bid >> 3);         // 512-block XCD swizzle
  const int NTt = isqk ? 8 : 64;
  const int ntile = wg % NTt, mtile = wg / NTt;
  const unsigned short* A  = isqk ? Xb : WvT;
  const unsigned short* Bt = isqk ? WqkT : Xb;
  void* C = isqk ? (void*)QKb : (void*)VT;
  const float* bias = isqk ? bqk : bv;
  const int ldc = isqk ? 1024 : 8192;
  gemm_core<1>(lds,
      A + (long)(mtile * 128) * 1024, 1024,
      Bt + (long)(ntile * 128) * 1024, 1024,
      C, ldc, 0, bias, isqk ? 1 : 2, 1.f, 1024,
      mtile * 128, ntile * 128);
}

// ------- row softmax over bf16 scores, in place: [8192][2048] bf16 -------
__global__ __launch_bounds__(256)
void softmax_rows_bf16(unsigned short* __restrict__ sc) {
  long row = blockIdx.x;
  unsigned short* p = sc + row * 2048;
  int tid = threadIdx.x;
  int wave = tid >> 6;

  ushort8 x = *(const ushort8*)(p + tid * 8);
  float v[8];
#pragma unroll
  for (int j = 0; j < 8; ++j) v[j] = bf2f(x[j]);

  float m = -1e30f;
#pragma unroll
  for (int j = 0; j < 8; ++j) m = fmaxf(m, v[j]);
#pragma unroll
  for (int o = 32; o; o >>= 1) m = fmaxf(m, __shfl_xor(m, o));
  __shared__ float redm[4], reds[4];
  if ((tid & 63) == 0) redm[wave] = m;
  __syncthreads();
  m = fmaxf(fmaxf(redm[0], redm[1]), fmaxf(redm[2], redm[3]));

  float s = 0.f;
#pragma unroll
  for (int j = 0; j < 8; ++j) { v[j] = __expf(v[j] - m); s += v[j]; }
#pragma unroll
  for (int o = 32; o; o >>= 1) s += __shfl_xor(s, o);
  if ((tid & 63) == 0) reds[wave] = s;
  __syncthreads();
  s = reds[0] + reds[1] + reds[2] + reds[3];
  float inv = 1.0f / s;

  ushort8 o8;
#pragma unroll
  for (int j = 0; j < 8; ++j) o8[j] = f2bf(v[j] * inv);
  *(ushort8*)(p + tid * 8) = o8;
}

// ------------------------------------------------------------------------------
extern "C" void kernel_launch(void* const* d_in, const int* in_sizes, int n_in,
                              void* d_out, int out_size, void* d_ws, size_t ws_size,
                              hipStream_t stream) {
  const float* X  = (const float*)d_in[0];
  const float* Wq = (const float*)d_in[1];
  const float* bq = (const float*)d_in[2];
  const float* Wk = (const float*)d_in[3];
  const float* bk = (const float*)d_in[4];
  const float* Wv = (const float*)d_in[5];
  const float* bv = (const float*)d_in[6];
  float* out = (float*)d_out;

  char* ws = (char*)d_ws;
  unsigned short* Xb   = (unsigned short*)(ws);                 // 16 MiB [8192,1024]
  unsigned short* WqkT = (unsigned short*)(ws + (16l << 20));   //  2 MiB [1024,1024]
  unsigned short* WvT  = (unsigned short*)(ws + (18l << 20));   //  2 MiB [1024,1024]
  float*          bqk  = (float*)         (ws + (20l << 20));   //  4 KiB [1024]
  unsigned short* QKb  = (unsigned short*)(ws + (21l << 20));   // 16 MiB [8192,1024]
  unsigned short* VT   = (unsigned short*)(ws + (37l << 20));   // 16 MiB [1024,8192]
  unsigned short* SC   = (unsigned short*)(ws + (53l << 20));   // 32 MiB [4][2048][2048] bf16

  // 1) merged prep (X convert + 3 transposes + bias concat)
  prep<<<4100, 256, 0, stream>>>(X, Xb, Wq, Wk, Wv, WqkT, WvT, bq, bk, bqk);

  // 2) merged projections: QKb = Xb*WqkT^T + bqk  |  VT = WvT*Xb^T + bv
  gemmProj<<<1024, 256, 0, stream>>>(Xb, WqkT, WvT, QKb, VT, bqk, bv);

  // 3) scores[b] = Q[b] K[b]^T / sqrt(512)  (bf16 out, batched; grid 1024)
  gemmC<1><<<1024, 256, 0, stream>>>(QKb, 1024, 2048l * 1024, QKb + 512, 1024, 2048l * 1024,
                                     SC, 2048, 2048l * 2048,
                                     0.044194173824159216f, 512, 16, 16);

  // 4) softmax rows, bf16 in-place
  softmax_rows_bf16<<<8192, 256, 0, stream>>>(SC);

  // 5) out[b] = P[b] V[b]  (A = P bf16 lda 2048; Bt = V^T batch slice; grid 512)
  gemmC<0><<<512, 256, 0, stream>>>(SC, 2048, 2048l * 2048, VT, 8192, 2048,
                                    out, 1024, 2048l * 1024,
                                    1.f, 2048, 16, 8);
}